// Round 9
// baseline (180.467 us; speedup 1.0000x reference)
//
#include <hip/hip_runtime.h>

#define MARGIN  0.3f
#define NEG_INF -1e30f
#define POS_INF  1e30f

#define NTH 512           // 8 waves, 2M x 4N
#define NBLK 256          // 16 x 16 tile grid, 1 block/CU

typedef __attribute__((ext_vector_type(8))) short bf16x8;
typedef __attribute__((ext_vector_type(4))) float f32x4;

// async global->LDS, 16B per lane (dest linear in lane; source is per-lane)
#define GLOAD_LDS16(g, l) __builtin_amdgcn_global_load_lds(                      \
    (const __attribute__((address_space(1))) void*)(g),                          \
    (__attribute__((address_space(3))) void*)(l), 16, 0, 0)

// ---- order-preserving float <-> uint mapping for atomic max/min ----
__device__ __forceinline__ unsigned f2ord(float f) {
    unsigned u = __float_as_uint(f);
    return (u & 0x80000000u) ? ~u : (u | 0x80000000u);
}
__device__ __forceinline__ float ord2f(unsigned u) {
    unsigned b = (u & 0x80000000u) ? (u ^ 0x80000000u) : ~u;
    return __uint_as_float(b);
}
__device__ __forceinline__ unsigned short f2bf(float f) {
    unsigned u = __float_as_uint(f);
    u += 0x7fffu + ((u >> 16) & 1u);
    return (unsigned short)(u >> 16);
}

// ---- kernel 1: fp32 -> bf16 convert + row sum-of-squares + init acc ----
__global__ __launch_bounds__(256)
void convert_kernel(const float* __restrict__ X, int d,
                    unsigned short* __restrict__ Xb,
                    float* __restrict__ sq,
                    unsigned* __restrict__ apk,
                    unsigned* __restrict__ ank,
                    unsigned* __restrict__ done) {
    const int row = blockIdx.x;
    const int tid = threadIdx.x;
    const float4* xr = (const float4*)(X + (size_t)row * d);
    float4 v0 = xr[tid * 2];
    float4 v1 = xr[tid * 2 + 1];
    float s = v0.x * v0.x + v0.y * v0.y + v0.z * v0.z + v0.w * v0.w
            + v1.x * v1.x + v1.y * v1.y + v1.z * v1.z + v1.w * v1.w;
    uint4 w;
    w.x = (unsigned)f2bf(v0.x) | ((unsigned)f2bf(v0.y) << 16);
    w.y = (unsigned)f2bf(v0.z) | ((unsigned)f2bf(v0.w) << 16);
    w.z = (unsigned)f2bf(v1.x) | ((unsigned)f2bf(v1.y) << 16);
    w.w = (unsigned)f2bf(v1.z) | ((unsigned)f2bf(v1.w) << 16);
    *(uint4*)(Xb + (size_t)row * d + tid * 8) = w;

    for (int off = 32; off; off >>= 1) s += __shfl_down(s, off);
    __shared__ float ws[4];
    int lane = tid & 63, wid = tid >> 6;
    if (lane == 0) ws[wid] = s;
    __syncthreads();
    if (tid == 0) {
        sq[row]  = ws[0] + ws[1] + ws[2] + ws[3];
        apk[row] = f2ord(NEG_INF);
        ank[row] = f2ord(POS_INF);
        if (row == 0) *done = 0u;
    }
}

// ---- kernel 2: 256x256 8-phase counted-vmcnt MFMA Gram tile + mining + loss ----
__global__ __launch_bounds__(NTH, 2)
void mfma_tile_kernel(const unsigned short* __restrict__ Xb,
                      const int* __restrict__ tgt,
                      const float* __restrict__ sq,
                      unsigned* __restrict__ apk, unsigned* __restrict__ ank,
                      unsigned* __restrict__ done, float* __restrict__ out,
                      int n, int d) {
    // [buf][half] 128 rows x 128B per half-tile, XOR-swizzled image
    __shared__ char Abuf[2][2][16384];
    __shared__ char Bbuf[2][2][16384];
    __shared__ float srow_s[256], scol_s[256];
    __shared__ int   trow_s[256], tcol_s[256];

    const int ntile = n / 256;               // 16
    // XCD-bijective swizzle: 256 blocks, 8 XCDs x 32
    int swz = ((int)blockIdx.x & 7) * (NBLK / 8) + ((int)blockIdx.x >> 3);
    const int bi = swz / ntile, bj = swz % ntile;
    const int row0 = bi * 256, col0 = bj * 256;

    const int tid  = threadIdx.x;
    const int lane = tid & 63, wid = tid >> 6;
    const int wr = wid >> 2, wc = wid & 3;   // 2x4 waves; wave owns 128x64 of C
    const int lr = lane & 15, lh = lane >> 4;
    const int brbase = (wc & 1) * 64;        // B-row base within B half-tile

    if (tid < 256) { srow_s[tid] = sq[row0 + tid]; trow_s[tid] = tgt[row0 + tid]; }
    else { int j = tid - 256; scol_s[j] = sq[col0 + j]; tcol_s[j] = tgt[col0 + j]; }

    f32x4 acc[8][4];
#pragma unroll
    for (int m = 0; m < 8; ++m)
#pragma unroll
        for (int nn = 0; nn < 4; ++nn) acc[m][nn] = (f32x4){0.f, 0.f, 0.f, 0.f};

    bf16x8 a[4][2], bfr[4][2];

    const size_t dstride = (size_t)d * 2;    // bf16 row stride in bytes
    const char* Arow = (const char*)Xb + (size_t)row0 * dstride;
    const char* Brow = (const char*)Xb + (size_t)col0 * dstride;

    // stage one 128x64 half-tile: 512 thr x 2 x 16B; dest linear, src inv-swizzled
#define STG(gpanel, lslot, tt, h)                                                \
    do {                                                                         \
        _Pragma("unroll")                                                        \
        for (int it = 0; it < 2; ++it) {                                         \
            int p = it * 8192 + tid * 16;                                        \
            int r = p >> 7, kbq = p & 127;                                       \
            int skb = kbq ^ ((r & 7) << 4);                                      \
            GLOAD_LDS16(gpanel + (size_t)((h) * 128 + r) * dstride               \
                               + (size_t)(tt) * 128 + skb,                       \
                        (char*)(lslot) + p);                                     \
        }                                                                        \
    } while (0)

#define LOAD_A(QM)                                                               \
    _Pragma("unroll")                                                            \
    for (int ma = 0; ma < 4; ++ma)                                               \
    { _Pragma("unroll")                                                          \
      for (int kk = 0; kk < 2; ++kk) {                                           \
        int rh = ((QM) * 4 + ma) * 16 + lr;                                      \
        a[ma][kk] = *(const bf16x8*)(Ap + rh * 128 +                             \
                       ((kk * 64 + lh * 16) ^ ((rh & 7) << 4)));                 \
    } }

#define LOAD_B(QN)                                                               \
    _Pragma("unroll")                                                            \
    for (int nb = 0; nb < 2; ++nb)                                               \
    { _Pragma("unroll")                                                          \
      for (int kk = 0; kk < 2; ++kk) {                                           \
        int rh = brbase + ((QN) * 2 + nb) * 16 + lr;                             \
        bfr[(QN) * 2 + nb][kk] = *(const bf16x8*)(Bp + rh * 128 +                \
                       ((kk * 64 + lh * 16) ^ ((rh & 7) << 4)));                 \
    } }

#define MFMA_Q(QM, QN)                                                           \
    _Pragma("unroll")                                                            \
    for (int ma = 0; ma < 4; ++ma)                                               \
    { _Pragma("unroll")                                                          \
      for (int nb = 0; nb < 2; ++nb)                                             \
      { _Pragma("unroll")                                                        \
        for (int kk = 0; kk < 2; ++kk)                                           \
          acc[(QM) * 4 + ma][(QN) * 2 + nb] =                                    \
              __builtin_amdgcn_mfma_f32_16x16x32_bf16(                           \
                  a[ma][kk], bfr[(QN) * 2 + nb][kk],                             \
                  acc[(QM) * 4 + ma][(QN) * 2 + nb], 0, 0, 0);                   \
    } }

    const int NKT = d >> 6;                  // 32 K-tiles of BK=64

    // ---- prologue: K0 fully + K1 minus A1h1 (7 half-tiles, oldest->newest) ----
    STG(Arow, Abuf[0][0], 0, 0);
    STG(Arow, Abuf[0][1], 0, 1);
    STG(Brow, Bbuf[0][0], 0, 0);
    STG(Brow, Bbuf[0][1], 0, 1);
    STG(Arow, Abuf[1][0], 1, 0);
    STG(Brow, Bbuf[1][0], 1, 0);
    STG(Brow, Bbuf[1][1], 1, 1);
    asm volatile("s_waitcnt vmcnt(6)" ::: "memory");   // K0 landed (6 newest fly)
    __builtin_amdgcn_s_barrier();

    for (int t = 0; t < NKT; ++t) {
        const char* Ap = (const char*)Abuf[t & 1][wr];
        const char* Bp = (const char*)Bbuf[t & 1][wc >> 1];
        // ---------- phase q0 ----------
        if (t + 1 < NKT) STG(Arow, Abuf[(t + 1) & 1][1], t + 1, 1);
        LOAD_A(0); LOAD_B(0);
        __builtin_amdgcn_s_barrier();
        asm volatile("s_waitcnt lgkmcnt(0)" ::: "memory");
        __builtin_amdgcn_sched_barrier(0);
        __builtin_amdgcn_s_setprio(1);
        MFMA_Q(0, 0);
        __builtin_amdgcn_s_setprio(0);
        __builtin_amdgcn_s_barrier();
        // ---------- phase q1 ----------
        LOAD_B(1);
        __builtin_amdgcn_s_barrier();
        asm volatile("s_waitcnt lgkmcnt(0)" ::: "memory");
        __builtin_amdgcn_sched_barrier(0);
        __builtin_amdgcn_s_setprio(1);
        MFMA_Q(0, 1);
        __builtin_amdgcn_s_setprio(0);
        __builtin_amdgcn_s_barrier();
        // ---------- phase q2 ---------- (B halves retired after q1)
        if (t + 2 < NKT) STG(Brow, Bbuf[t & 1][0], t + 2, 0);
        LOAD_A(1);
        __builtin_amdgcn_s_barrier();
        asm volatile("s_waitcnt lgkmcnt(0)" ::: "memory");
        __builtin_amdgcn_sched_barrier(0);
        __builtin_amdgcn_s_setprio(1);
        MFMA_Q(1, 0);
        __builtin_amdgcn_s_setprio(0);
        __builtin_amdgcn_s_barrier();
        // ---------- phase q3 ---------- (A-h0 retired after q2)
        if (t + 2 < NKT) {
            STG(Brow, Bbuf[t & 1][1], t + 2, 1);
            STG(Arow, Abuf[t & 1][0], t + 2, 0);
        }
        if (t < NKT - 2)       asm volatile("s_waitcnt vmcnt(6)" ::: "memory");
        else if (t == NKT - 2) asm volatile("s_waitcnt vmcnt(0)" ::: "memory");
        __builtin_amdgcn_s_barrier();
        __builtin_amdgcn_s_setprio(1);
        MFMA_Q(1, 1);
        __builtin_amdgcn_s_setprio(0);
        __builtin_amdgcn_s_barrier();
    }
#undef STG
#undef LOAD_A
#undef LOAD_B
#undef MFMA_Q

    // ---- epilogue: dist = sq_i + sq_j - 2*ip; row mining (full matrix) ----
    float sc[4]; int tc[4];
#pragma unroll
    for (int nn = 0; nn < 4; ++nn) {
        int cl = wc * 64 + nn * 16 + lr;
        sc[nn] = scol_s[cl]; tc[nn] = tcol_s[cl];
    }
#pragma unroll
    for (int m = 0; m < 8; ++m) {
#pragma unroll
        for (int j = 0; j < 4; ++j) {
            int rl = wr * 128 + m * 16 + lh * 4 + j;
            float sr = srow_s[rl];
            int   tr = trow_s[rl];
            float av = NEG_INF, vv = POS_INF;
#pragma unroll
            for (int nn = 0; nn < 4; ++nn) {
                float dist = sr + sc[nn] - 2.0f * acc[m][nn][j];
                bool same = (tr == tc[nn]);
                av = fmaxf(av, same ? dist : NEG_INF);
                vv = fminf(vv, same ? POS_INF : dist);
            }
#pragma unroll
            for (int off = 1; off < 16; off <<= 1) {
                av = fmaxf(av, __shfl_xor(av, off));
                vv = fminf(vv, __shfl_xor(vv, off));
            }
            if (lr == 0) {
                atomicMax(&apk[row0 + rl], f2ord(av));
                atomicMin(&ank[row0 + rl], f2ord(vv));
            }
        }
    }

    // ---- last-block loss reduction: mean(relu(ap - an + margin)) ----
    __shared__ int is_last;
    __threadfence();                          // mining atomics visible before ticket
    if (tid == 0) {
        unsigned old = atomicAdd(done, 1u);
        is_last = (old == (unsigned)(NBLK - 1));
    }
    __syncthreads();
    if (is_last) {
        float s = 0.f;
        for (int i = tid; i < n; i += NTH) {
            float ap = ord2f(atomicAdd(&apk[i], 0u));   // coherent read
            float an = ord2f(atomicAdd(&ank[i], 0u));
            s += fmaxf(ap - an + MARGIN, 0.0f);
        }
        for (int off = 32; off; off >>= 1) s += __shfl_down(s, off);
        __shared__ float lws[8];
        if (lane == 0) lws[wid] = s;
        __syncthreads();
        if (tid == 0) {
            float tsum = 0.f;
            for (int w = 0; w < 8; ++w) tsum += lws[w];
            out[0] = tsum / (float)n;
        }
    }
}

extern "C" void kernel_launch(void* const* d_in, const int* in_sizes, int n_in,
                              void* d_out, int out_size, void* d_ws, size_t ws_size,
                              hipStream_t stream) {
    const float* X   = (const float*)d_in[0];
    const int*   tgt = (const int*)d_in[1];
    const int n = in_sizes[1];
    const int d = in_sizes[0] / n;

    float*    sq   = (float*)d_ws;
    unsigned* apk  = (unsigned*)((char*)d_ws + (size_t)n * 4);
    unsigned* ank  = apk + n;
    unsigned* done = (unsigned*)((char*)d_ws + (size_t)n * 12);
    unsigned short* Xb = (unsigned short*)((char*)d_ws + (size_t)n * 12 + 16);

    convert_kernel<<<n, 256, 0, stream>>>(X, d, Xb, sq, apk, ank, done);
    mfma_tile_kernel<<<NBLK, NTH, 0, stream>>>(Xb, tgt, sq, apk, ank, done,
                                               (float*)d_out, n, d);
}